// Round 3
// baseline (394.301 us; speedup 1.0000x reference)
//
#include <hip/hip_runtime.h>
#include <hip/hip_bf16.h>

// Gather + concat: out[b, 0:512]    = lstm1[b, input_length[b]-1, :]
//                  out[b, 512:1024] = lstm2[b, support_length[b]-1, :]
// B=64, T=2048, H=512, f32.

#define B_SZ 64
#define T_SZ 2048L
#define H_SZ 512L

// LEN_MODE: 0 = sniff on device, 1 = int32 layout, 2 = little-endian int64.
// Lengths are in [1, T] (never 0), so for the sniff: if int32 word 1 is 0,
// the buffer is LE int64 (word 1 = high half of element 0); else int32.
__device__ __forceinline__ long load_len(const int* __restrict__ p, int b, int mode) {
    if (mode == 1) return (long)p[b];
    if (mode == 2) return (long)p[2 * b];
    return (p[1] == 0) ? (long)p[2 * b] : (long)p[b];
}

__global__ void __launch_bounds__(256)
vlos_gather_kernel(const float* __restrict__ l1,
                   const float* __restrict__ l2,
                   const int*   __restrict__ ilen,
                   const int*   __restrict__ slen,
                   float*       __restrict__ out,
                   int len_mode) {
    const int b = blockIdx.x;    // 0..63
    const int t = threadIdx.x;   // 0..255, each moves one float4 (16 B)

    const long TH = T_SZ * H_SZ;

    const float4* src;
    if (t < 128) {
        const long len1 = load_len(ilen, b, len_mode);
        src = reinterpret_cast<const float4*>(l1 + (long)b * TH + (len1 - 1) * H_SZ) + t;
    } else {
        const long len2 = load_len(slen, b, len_mode);
        src = reinterpret_cast<const float4*>(l2 + (long)b * TH + (len2 - 1) * H_SZ) + (t - 128);
    }

    float4 v = *src;
    reinterpret_cast<float4*>(out + (long)b * 2 * H_SZ)[t] = v;
}

extern "C" void kernel_launch(void* const* d_in, const int* in_sizes, int n_in,
                              void* d_out, int out_size, void* d_ws, size_t ws_size,
                              hipStream_t stream) {
    const float* l1   = (const float*)d_in[0];
    const float* l2   = (const float*)d_in[1];
    const int*   ilen = (const int*)d_in[2];
    const int*   slen = (const int*)d_in[3];
    float* out = (float*)d_out;

    // If the harness reports element counts for the length arrays, use them
    // to pin the layout: B int32 words -> int32; 2*B words -> int64 halves.
    // Only a doubled count is unambiguous; otherwise sniff on device.
    int len_mode = 0;
    if (n_in >= 3 && in_sizes[2] == 2 * B_SZ) len_mode = 2;

    vlos_gather_kernel<<<B_SZ, 256, 0, stream>>>(l1, l2, ilen, slen, out, len_mode);
}